// Round 2
// baseline (847.852 us; speedup 1.0000x reference)
//
#include <hip/hip_runtime.h>

#define NROWS 131072
#define DIM 64
#define KCODES 1024
#define TM 128   // rows per block in pass A
#define TN 64    // codes per LDS chunk
#define MARGIN 2e-3f

// ---------------- init: zero accumulators ----------------
__global__ void vq_init(double* loss_accum, int* flag_count) {
  *loss_accum = 0.0;
  *flag_count = 0;
}

// ---------------- embedding norms (f64 + f32) ----------------
__global__ void vq_enorm(const float* __restrict__ emb,
                         double* __restrict__ enorm64,
                         float* __restrict__ enorm32) {
  int k = blockIdx.x * blockDim.x + threadIdx.x;
  if (k >= KCODES) return;
  double s = 0.0;
  for (int d = 0; d < DIM; d++) {
    double e = (double)emb[k * DIM + d];
    s = fma(e, e, s);
  }
  enorm64[k] = s;
  enorm32[k] = (float)s;
}

// ---------------- pass A: f32 distance GEMM + running top-2 min ----------------
// block = 256 threads, tile = 128 rows x all 1024 codes (chunks of 64)
// thread (cg = t&15, rg = t>>4) owns 8 rows x 4 codes per chunk.
__global__ __launch_bounds__(256) void vq_passA(
    const float* __restrict__ z, const float* __restrict__ emb,
    const float* __restrict__ enorm32, float* __restrict__ idx_f,
    int* __restrict__ flag_count, int* __restrict__ flag_rows) {
  __shared__ float zT[DIM][132];  // transposed z tile, padded (16B-aligned rows)
  __shared__ float eT[DIM][68];   // transposed emb chunk, padded
  const int t = threadIdx.x;
  const int row0 = blockIdx.x * TM;

  // load z tile transposed (coalesced global reads)
  for (int i = t; i < TM * DIM; i += 256) {
    int r = i >> 6, d = i & 63;
    zT[d][r] = z[(size_t)(row0 + r) * DIM + d];
  }

  const int cg = t & 15;   // code group: codes kc + cg*4 .. +3
  const int rg = t >> 4;   // row group: rows rg*8 .. +7
  float min1[8], min2[8];
  int idx1[8];
#pragma unroll
  for (int i = 0; i < 8; i++) { min1[i] = 3.4e38f; min2[i] = 3.4e38f; idx1[i] = 0; }

  for (int kc = 0; kc < KCODES; kc += TN) {
    __syncthreads();
    for (int i = t; i < TN * DIM; i += 256) {
      int c = i >> 6, d = i & 63;
      eT[d][c] = emb[(size_t)(kc + c) * DIM + d];
    }
    __syncthreads();

    float acc[8][4];
#pragma unroll
    for (int r = 0; r < 8; r++)
#pragma unroll
      for (int c = 0; c < 4; c++) acc[r][c] = 0.f;

#pragma unroll 8
    for (int d = 0; d < DIM; d++) {
      float4 zv0 = *(const float4*)&zT[d][rg * 8];
      float4 zv1 = *(const float4*)&zT[d][rg * 8 + 4];
      float4 ev = *(const float4*)&eT[d][cg * 4];
      float zr[8] = {zv0.x, zv0.y, zv0.z, zv0.w, zv1.x, zv1.y, zv1.z, zv1.w};
      float ec[4] = {ev.x, ev.y, ev.z, ev.w};
#pragma unroll
      for (int r = 0; r < 8; r++)
#pragma unroll
        for (int c = 0; c < 4; c++) acc[r][c] = fmaf(zr[r], ec[c], acc[r][c]);
    }

    // fold into running top-2 mins (codes ascend per thread -> strict < keeps first-min)
#pragma unroll
    for (int c = 0; c < 4; c++) {
      int code = kc + cg * 4 + c;
      float en = enorm32[code];
#pragma unroll
      for (int r = 0; r < 8; r++) {
        float s = fmaf(-2.f, acc[r][c], en);
        if (s < min1[r]) { min2[r] = min1[r]; min1[r] = s; idx1[r] = code; }
        else if (s < min2[r]) { min2[r] = s; }
      }
    }
  }

  // ---- cross-thread reduction over the 16 code-groups per row (reuse zT LDS) ----
  __syncthreads();
  float* red1 = &zT[0][0];        // [128][16]
  float* red2 = red1 + TM * 16;   // [128][16]
  int* redi = (int*)(red2 + TM * 16);
#pragma unroll
  for (int r = 0; r < 8; r++) {
    int rl = rg * 8 + r;
    red1[rl * 16 + cg] = min1[r];
    red2[rl * 16 + cg] = min2[r];
    redi[rl * 16 + cg] = idx1[r];
  }
  __syncthreads();
  if (t < TM) {
    float m1 = red1[t * 16], m2 = red2[t * 16];
    int ix = redi[t * 16];
    for (int g = 1; g < 16; g++) {
      float a1 = red1[t * 16 + g];
      float a2 = red2[t * 16 + g];
      int ai = redi[t * 16 + g];
      if (a1 < m1) { m2 = fminf(m1, a2); m1 = a1; ix = ai; }
      else { m2 = fminf(m2, a1); }
    }
    int row = row0 + t;
    idx_f[row] = (float)ix;
    // any row whose top-2 gap is small enough that numpy-f32's rounding could
    // pick a different winner (np per-k error ~1e-5 << MARGIN) gets refined
    if (m2 - m1 < MARGIN) {
      int pos = atomicAdd(flag_count, 1);
      if (pos < NROWS) flag_rows[pos] = row;
    }
  }
}

// ---------------- refine flagged rows: replicate numpy-f32 rounding pipeline ----------------
// dist32[k] = f32( f32(A32 + B32[k]) - f32(2 * dot_f64) ), argmin lowest-index-on-tie.
// dot in f64 (error << ulp of sgemm-f32 dist grid); final ops in f32 exactly as numpy.
__global__ void vq_refine(const float* __restrict__ z, const float* __restrict__ emb,
                          const double* __restrict__ enorm64,
                          const int* __restrict__ flag_count,
                          const int* __restrict__ flag_rows,
                          float* __restrict__ idx_f) {
  __shared__ float zs[DIM];
  __shared__ float bestv[64];
  __shared__ int bidx[64];
  __shared__ float A32s;
  int cnt = *flag_count;
  if (cnt > NROWS) cnt = NROWS;
  int t = threadIdx.x;
  for (int i = blockIdx.x; i < cnt; i += gridDim.x) {
    int row = flag_rows[i];
    zs[t] = z[(size_t)row * DIM + t];
    __syncthreads();
    if (t == 0) {
      double a = 0.0;
      for (int d = 0; d < DIM; d++) {
        double v = (double)zs[d];
        a = fma(v, v, a);
      }
      A32s = (float)a;  // f32 row norm (exact value irrelevant mod grid-aligned shift)
    }
    __syncthreads();
    float A32 = A32s;
    float bm = 3.4e38f;
    int bi = 0;
    for (int k = t; k < KCODES; k += 64) {
      double dot = 0.0;
      for (int d = 0; d < DIM; d++)
        dot = fma((double)emb[(size_t)k * DIM + d], (double)zs[d], dot);
      float C = (float)(2.0 * dot);      // f32 "2.0 * z@e.T" entry
      float B = (float)enorm64[k];       // f32 ||e_k||^2
      float T = A32 + B;                 // f32 add (numpy broadcast add)
      float dist = T - C;                // f32 subtract -> quantized dist
      if (dist < bm) { bm = dist; bi = k; }  // strict <: lowest k wins ties in-thread
    }
    bestv[t] = bm; bidx[t] = bi;
    __syncthreads();
    if (t == 0) {
      float m = bestv[0]; int ix = bidx[0];
      for (int l = 1; l < 64; l++)
        if (bestv[l] < m || (bestv[l] == m && bidx[l] < ix)) { m = bestv[l]; ix = bidx[l]; }
      idx_f[row] = (float)ix;
    }
    __syncthreads();
  }
}

// ---------------- outputs: quantized_ste + loss partials ----------------
__global__ __launch_bounds__(256) void vq_outputs(
    const float* __restrict__ z, const float* __restrict__ emb,
    const float* __restrict__ idx_f, float* __restrict__ out_q,
    double* __restrict__ loss_accum) {
  int t = threadIdx.x;
  int row = blockIdx.x * 4 + (t >> 6);
  int d = t & 63;
  float zv = z[(size_t)row * DIM + d];
  int k = (int)idx_f[row];
  float q = emb[(size_t)k * DIM + d];
  float diff = q - zv;
  out_q[(size_t)row * DIM + d] = zv + diff;  // straight-through value == quantized
  double v = (double)diff * (double)diff;
  __shared__ double red[256];
  red[t] = v;
  __syncthreads();
  for (int s = 128; s > 0; s >>= 1) {
    if (t < s) red[t] += red[t + s];
    __syncthreads();
  }
  if (t == 0) atomicAdd(loss_accum, red[0]);
}

__global__ void vq_final(const double* __restrict__ loss_accum,
                         float* __restrict__ out_loss) {
  *out_loss = (float)(1.5 * (*loss_accum) / (double)(NROWS * DIM));
}

extern "C" void kernel_launch(void* const* d_in, const int* in_sizes, int n_in,
                              void* d_out, int out_size, void* d_ws, size_t ws_size,
                              hipStream_t stream) {
  const float* z = (const float*)d_in[0];
  const float* emb = (const float*)d_in[1];
  float* out = (float*)d_out;
  float* out_q = out;                      // 8388608 floats
  float* out_loss = out + 8388608;         // 1 float
  float* idx_f = out + 8388609;            // 131072 floats (indices as float)

  char* ws = (char*)d_ws;
  double* loss_accum = (double*)ws;                        // 8 B
  double* enorm64 = (double*)(ws + 8);                     // 8 KB
  int* flag_count = (int*)(ws + 8 + 8192);                 // 4 B (+12 pad)
  float* enorm32 = (float*)(ws + 8 + 8192 + 16);           // 4 KB
  int* flag_rows = (int*)(ws + 8 + 8192 + 16 + 4096);      // 512 KB

  vq_init<<<1, 1, 0, stream>>>(loss_accum, flag_count);
  vq_enorm<<<16, 64, 0, stream>>>(emb, enorm64, enorm32);
  vq_passA<<<NROWS / TM, 256, 0, stream>>>(z, emb, enorm32, idx_f, flag_count, flag_rows);
  vq_refine<<<128, 64, 0, stream>>>(z, emb, enorm64, flag_count, flag_rows, idx_f);
  vq_outputs<<<NROWS / 4, 256, 0, stream>>>(z, emb, idx_f, out_q, loss_accum);
  vq_final<<<1, 1, 0, stream>>>(loss_accum, out_loss);
}

// Round 3
// 411.784 us; speedup vs baseline: 2.0590x; 2.0590x over previous
//
#include <hip/hip_runtime.h>

#define NROWS 131072
#define DIM 64
#define KCODES 1024
#define TM 128   // rows per block in pass A
#define TN 64    // codes per LDS chunk
#define MARGIN 2e-3f
#define OUT_BLOCKS 2048

// ---------------- init: zero flag counter ----------------
__global__ void vq_init(int* flag_count) {
  *flag_count = 0;
}

// ---------------- embedding norms (f64 + f32) ----------------
__global__ void vq_enorm(const float* __restrict__ emb,
                         double* __restrict__ enorm64,
                         float* __restrict__ enorm32) {
  int k = blockIdx.x * blockDim.x + threadIdx.x;
  if (k >= KCODES) return;
  double s = 0.0;
  for (int d = 0; d < DIM; d++) {
    double e = (double)emb[k * DIM + d];
    s = fma(e, e, s);
  }
  enorm64[k] = s;
  enorm32[k] = (float)s;
}

// ---------------- pass A: f32 distance GEMM + running top-2 min ----------------
__global__ __launch_bounds__(256) void vq_passA(
    const float* __restrict__ z, const float* __restrict__ emb,
    const float* __restrict__ enorm32, float* __restrict__ idx_f,
    int* __restrict__ flag_count, int* __restrict__ flag_rows) {
  __shared__ float zT[DIM][132];  // transposed z tile, padded
  __shared__ float eT[DIM][68];   // transposed emb chunk, padded
  const int t = threadIdx.x;
  const int row0 = blockIdx.x * TM;

  for (int i = t; i < TM * DIM; i += 256) {
    int r = i >> 6, d = i & 63;
    zT[d][r] = z[(size_t)(row0 + r) * DIM + d];
  }

  const int cg = t & 15;
  const int rg = t >> 4;
  float min1[8], min2[8];
  int idx1[8];
#pragma unroll
  for (int i = 0; i < 8; i++) { min1[i] = 3.4e38f; min2[i] = 3.4e38f; idx1[i] = 0; }

  for (int kc = 0; kc < KCODES; kc += TN) {
    __syncthreads();
    for (int i = t; i < TN * DIM; i += 256) {
      int c = i >> 6, d = i & 63;
      eT[d][c] = emb[(size_t)(kc + c) * DIM + d];
    }
    __syncthreads();

    float acc[8][4];
#pragma unroll
    for (int r = 0; r < 8; r++)
#pragma unroll
      for (int c = 0; c < 4; c++) acc[r][c] = 0.f;

#pragma unroll 8
    for (int d = 0; d < DIM; d++) {
      float4 zv0 = *(const float4*)&zT[d][rg * 8];
      float4 zv1 = *(const float4*)&zT[d][rg * 8 + 4];
      float4 ev = *(const float4*)&eT[d][cg * 4];
      float zr[8] = {zv0.x, zv0.y, zv0.z, zv0.w, zv1.x, zv1.y, zv1.z, zv1.w};
      float ec[4] = {ev.x, ev.y, ev.z, ev.w};
#pragma unroll
      for (int r = 0; r < 8; r++)
#pragma unroll
        for (int c = 0; c < 4; c++) acc[r][c] = fmaf(zr[r], ec[c], acc[r][c]);
    }

#pragma unroll
    for (int c = 0; c < 4; c++) {
      int code = kc + cg * 4 + c;
      float en = enorm32[code];
#pragma unroll
      for (int r = 0; r < 8; r++) {
        float s = fmaf(-2.f, acc[r][c], en);
        if (s < min1[r]) { min2[r] = min1[r]; min1[r] = s; idx1[r] = code; }
        else if (s < min2[r]) { min2[r] = s; }
      }
    }
  }

  __syncthreads();
  float* red1 = &zT[0][0];
  float* red2 = red1 + TM * 16;
  int* redi = (int*)(red2 + TM * 16);
#pragma unroll
  for (int r = 0; r < 8; r++) {
    int rl = rg * 8 + r;
    red1[rl * 16 + cg] = min1[r];
    red2[rl * 16 + cg] = min2[r];
    redi[rl * 16 + cg] = idx1[r];
  }
  __syncthreads();
  if (t < TM) {
    float m1 = red1[t * 16], m2 = red2[t * 16];
    int ix = redi[t * 16];
    for (int g = 1; g < 16; g++) {
      float a1 = red1[t * 16 + g];
      float a2 = red2[t * 16 + g];
      int ai = redi[t * 16 + g];
      if (a1 < m1) { m2 = fminf(m1, a2); m1 = a1; ix = ai; }
      else { m2 = fminf(m2, a1); }
    }
    int row = row0 + t;
    idx_f[row] = (float)ix;
    if (m2 - m1 < MARGIN) {
      int pos = atomicAdd(flag_count, 1);
      if (pos < NROWS) flag_rows[pos] = row;
    }
  }
}

// ---------------- refine flagged rows: replicate numpy-f32 rounding pipeline ----------------
__global__ void vq_refine(const float* __restrict__ z, const float* __restrict__ emb,
                          const double* __restrict__ enorm64,
                          const int* __restrict__ flag_count,
                          const int* __restrict__ flag_rows,
                          float* __restrict__ idx_f) {
  __shared__ float zs[DIM];
  __shared__ float bestv[64];
  __shared__ int bidx[64];
  __shared__ float A32s;
  int cnt = *flag_count;
  if (cnt > NROWS) cnt = NROWS;
  int t = threadIdx.x;
  for (int i = blockIdx.x; i < cnt; i += gridDim.x) {
    int row = flag_rows[i];
    zs[t] = z[(size_t)row * DIM + t];
    __syncthreads();
    if (t == 0) {
      double a = 0.0;
      for (int d = 0; d < DIM; d++) {
        double v = (double)zs[d];
        a = fma(v, v, a);
      }
      A32s = (float)a;
    }
    __syncthreads();
    float A32 = A32s;
    float bm = 3.4e38f;
    int bi = 0;
    for (int k = t; k < KCODES; k += 64) {
      double dot = 0.0;
      for (int d = 0; d < DIM; d++)
        dot = fma((double)emb[(size_t)k * DIM + d], (double)zs[d], dot);
      float C = (float)(2.0 * dot);
      float B = (float)enorm64[k];
      float T = A32 + B;
      float dist = T - C;
      if (dist < bm) { bm = dist; bi = k; }
    }
    bestv[t] = bm; bidx[t] = bi;
    __syncthreads();
    if (t == 0) {
      float m = bestv[0]; int ix = bidx[0];
      for (int l = 1; l < 64; l++)
        if (bestv[l] < m || (bestv[l] == m && bidx[l] < ix)) { m = bestv[l]; ix = bidx[l]; }
      idx_f[row] = (float)ix;
    }
    __syncthreads();
  }
}

// ---------------- outputs: quantized_ste + per-block loss partials (no atomics) ----------------
// 2048 blocks x 256 threads, 4 float4 elements/thread, wave shuffle reduce.
__global__ __launch_bounds__(256) void vq_outputs(
    const float4* __restrict__ z4, const float4* __restrict__ emb4,
    const float* __restrict__ idx_f, float4* __restrict__ out4,
    double* __restrict__ partials) {
  const int tid = threadIdx.x;
  const int g0 = blockIdx.x * 256 + tid;
  double sum = 0.0;
#pragma unroll
  for (int it = 0; it < 4; ++it) {
    int e = g0 + it * (OUT_BLOCKS * 256);   // < 2097152 exactly
    int row = e >> 4;                        // 16 float4 per row
    int d4 = e & 15;
    int k = (int)idx_f[row];
    float4 zv = z4[e];
    float4 qv = emb4[k * 16 + d4];
    float dx = qv.x - zv.x, dy = qv.y - zv.y;
    float dz = qv.z - zv.z, dw = qv.w - zv.w;
    float4 o;
    o.x = zv.x + dx; o.y = zv.y + dy; o.z = zv.z + dz; o.w = zv.w + dw;
    out4[e] = o;
    sum += (double)dx * dx + (double)dy * dy + (double)dz * dz + (double)dw * dw;
  }
  // wave-level reduction (64 lanes)
  for (int off = 32; off > 0; off >>= 1)
    sum += __shfl_down(sum, off, 64);
  __shared__ double wsum[4];
  if ((tid & 63) == 0) wsum[tid >> 6] = sum;
  __syncthreads();
  if (tid == 0) partials[blockIdx.x] = wsum[0] + wsum[1] + wsum[2] + wsum[3];
}

// ---------------- final: sum partials, emit loss ----------------
__global__ __launch_bounds__(256) void vq_final(const double* __restrict__ partials,
                                                float* __restrict__ out_loss) {
  int t = threadIdx.x;
  double s = 0.0;
  for (int i = t; i < OUT_BLOCKS; i += 256) s += partials[i];
  for (int off = 32; off > 0; off >>= 1)
    s += __shfl_down(s, off, 64);
  __shared__ double wsum[4];
  if ((t & 63) == 0) wsum[t >> 6] = s;
  __syncthreads();
  if (t == 0) {
    double total = wsum[0] + wsum[1] + wsum[2] + wsum[3];
    *out_loss = (float)(1.5 * total / (double)((size_t)NROWS * DIM));
  }
}

extern "C" void kernel_launch(void* const* d_in, const int* in_sizes, int n_in,
                              void* d_out, int out_size, void* d_ws, size_t ws_size,
                              hipStream_t stream) {
  const float* z = (const float*)d_in[0];
  const float* emb = (const float*)d_in[1];
  float* out = (float*)d_out;
  float* out_q = out;                      // 8388608 floats
  float* out_loss = out + 8388608;         // 1 float
  float* idx_f = out + 8388609;            // 131072 floats (indices as float)

  char* ws = (char*)d_ws;
  double* partials = (double*)ws;                          // 16 KB (2048 doubles)
  double* enorm64 = (double*)(ws + 16384);                 // 8 KB
  int* flag_count = (int*)(ws + 16384 + 8192);             // 4 B (+12 pad)
  float* enorm32 = (float*)(ws + 16384 + 8192 + 16);       // 4 KB
  int* flag_rows = (int*)(ws + 16384 + 8192 + 16 + 4096);  // 512 KB

  vq_init<<<1, 1, 0, stream>>>(flag_count);
  vq_enorm<<<16, 64, 0, stream>>>(emb, enorm64, enorm32);
  vq_passA<<<NROWS / TM, 256, 0, stream>>>(z, emb, enorm32, idx_f, flag_count, flag_rows);
  vq_refine<<<256, 64, 0, stream>>>(z, emb, enorm64, flag_count, flag_rows, idx_f);
  vq_outputs<<<OUT_BLOCKS, 256, 0, stream>>>((const float4*)z, (const float4*)emb,
                                             idx_f, (float4*)out_q, partials);
  vq_final<<<1, 256, 0, stream>>>(partials, out_loss);
}

// Round 4
// 264.379 us; speedup vs baseline: 3.2070x; 1.5576x over previous
//
#include <hip/hip_runtime.h>

#define NROWS 131072
#define DIM 64
#define KCODES 1024
#define MARGIN_DOT 6e-3f
#define FLAG_CAP 16384
#define OUT_BLOCKS 2048

typedef short bf16x8 __attribute__((ext_vector_type(8)));
typedef float f32x4 __attribute__((ext_vector_type(4)));

__device__ __forceinline__ unsigned short f32_to_bf16_rne(float f) {
  unsigned u = __float_as_uint(f);
  u += 0x7FFFu + ((u >> 16) & 1u);
  return (unsigned short)(u >> 16);
}

// ---------------- init ----------------
__global__ void vq_init(int* flag_count) { *flag_count = 0; }

// ---------------- prep: enorm64 + split-bf16 emb planes ----------------
__global__ __launch_bounds__(64) void vq_prep(const float* __restrict__ emb,
                                              double* __restrict__ enorm64,
                                              unsigned short* __restrict__ e_hi,
                                              unsigned short* __restrict__ e_lo) {
  int k = blockIdx.x;
  int d = threadIdx.x;
  float v = emb[k * 64 + d];
  unsigned short h = f32_to_bf16_rne(v);
  float hf = __uint_as_float((unsigned)h << 16);
  e_hi[k * 64 + d] = h;
  e_lo[k * 64 + d] = f32_to_bf16_rne(v - hf);
  double s = (double)v * (double)v;
  for (int off = 32; off > 0; off >>= 1) s += __shfl_down(s, off, 64);
  if (d == 0) enorm64[k] = s;
}

// ---------------- pass B: split-bf16 MFMA argmax-dot + packed top-2 ----------------
// 512 blocks x 4 waves; wave owns 64 rows x all 1024 codes. No LDS, no barriers.
// MFMA: A = emb codes (i), B = z rows (j). C/D: j = lane&15, i = (lane>>4)*4+reg.
__global__ __launch_bounds__(256) void vq_passB(
    const float* __restrict__ z, const unsigned short* __restrict__ e_hi,
    const unsigned short* __restrict__ e_lo, float* __restrict__ idx_f,
    int* __restrict__ flag_count, int* __restrict__ flag_rows) {
  const int lane = threadIdx.x & 63;
  const int wv = threadIdx.x >> 6;
  const int rowbase = (blockIdx.x * 4 + wv) * 64;
  const int lo4 = lane & 15;
  const int hi4 = lane >> 4;

  // z fragments: row = rowbase + rt*16 + lo4, dims = ks*32 + hi4*8 .. +7 (contiguous 8)
  bf16x8 zh[4][2], zl[4][2];
#pragma unroll
  for (int rt = 0; rt < 4; rt++) {
    const float* zr = z + (size_t)(rowbase + rt * 16 + lo4) * 64;
#pragma unroll
    for (int ks = 0; ks < 2; ks++) {
      int d0 = ks * 32 + hi4 * 8;
      float4 f0 = *(const float4*)(zr + d0);
      float4 f1 = *(const float4*)(zr + d0 + 4);
      float fv[8] = {f0.x, f0.y, f0.z, f0.w, f1.x, f1.y, f1.z, f1.w};
      union { bf16x8 v; unsigned short u[8]; } H, L;
#pragma unroll
      for (int i = 0; i < 8; i++) {
        unsigned short h = f32_to_bf16_rne(fv[i]);
        float hf = __uint_as_float((unsigned)h << 16);
        H.u[i] = h;
        L.u[i] = f32_to_bf16_rne(fv[i] - hf);
      }
      zh[rt][ks] = H.v;
      zl[rt][ks] = L.v;
    }
  }

  float m1[4], m2[4];
#pragma unroll
  for (int rt = 0; rt < 4; rt++) { m1[rt] = -3.4e38f; m2[rt] = -3.4e38f; }

  // emb fragment base: code = ct*16 + lo4, dims hi4*8 (+32 for kstep 1)
  const unsigned short* pH = e_hi + (size_t)lo4 * 64 + hi4 * 8;
  const unsigned short* pL = e_lo + (size_t)lo4 * 64 + hi4 * 8;
  bf16x8 ah0 = *(const bf16x8*)(pH);
  bf16x8 ah1 = *(const bf16x8*)(pH + 32);
  bf16x8 al0 = *(const bf16x8*)(pL);
  bf16x8 al1 = *(const bf16x8*)(pL + 32);

  for (int ct = 0; ct < 64; ct++) {
    int nxt = (ct < 63 ? ct + 1 : 63) * (16 * 64);  // prefetch next code-tile
    bf16x8 nh0 = *(const bf16x8*)(pH + nxt);
    bf16x8 nh1 = *(const bf16x8*)(pH + nxt + 32);
    bf16x8 nl0 = *(const bf16x8*)(pL + nxt);
    bf16x8 nl1 = *(const bf16x8*)(pL + nxt + 32);
    const int cbase = ct * 16 + hi4 * 4;
#pragma unroll
    for (int rt = 0; rt < 4; rt++) {
      f32x4 acc = {0.f, 0.f, 0.f, 0.f};
      acc = __builtin_amdgcn_mfma_f32_16x16x32_bf16(ah0, zh[rt][0], acc, 0, 0, 0);
      acc = __builtin_amdgcn_mfma_f32_16x16x32_bf16(ah1, zh[rt][1], acc, 0, 0, 0);
      acc = __builtin_amdgcn_mfma_f32_16x16x32_bf16(al0, zh[rt][0], acc, 0, 0, 0);
      acc = __builtin_amdgcn_mfma_f32_16x16x32_bf16(al1, zh[rt][1], acc, 0, 0, 0);
      acc = __builtin_amdgcn_mfma_f32_16x16x32_bf16(ah0, zl[rt][0], acc, 0, 0, 0);
      acc = __builtin_amdgcn_mfma_f32_16x16x32_bf16(ah1, zl[rt][1], acc, 0, 0, 0);
      // fold: lane's 4 accs = codes cbase..cbase+3, same z-row (rowbase+rt*16+lo4)
#pragma unroll
      for (int r = 0; r < 4; r++) {
        unsigned cu = (__float_as_uint(acc[r]) & 0xFFFFFC00u) | (unsigned)(cbase + r);
        float p = __uint_as_float(cu);
        float pm = fminf(m1[rt], p);
        m1[rt] = fmaxf(m1[rt], p);
        m2[rt] = fmaxf(m2[rt], pm);
      }
    }
    ah0 = nh0; ah1 = nh1; al0 = nl0; al1 = nl1;
  }

  // merge the 4 lane-groups per row (xor 16, 32); row j lives in lanes {j,16+j,32+j,48+j}
#pragma unroll
  for (int rt = 0; rt < 4; rt++) {
    float a1 = m1[rt], a2 = m2[rt];
#pragma unroll
    for (int off = 16; off <= 32; off <<= 1) {
      float b1 = __shfl_xor(a1, off, 64);
      float b2 = __shfl_xor(a2, off, 64);
      float pm = fminf(a1, b1);
      a1 = fmaxf(a1, b1);
      a2 = fmaxf(fmaxf(a2, b2), pm);
    }
    if (lane < 16) {
      int row = rowbase + rt * 16 + lane;
      idx_f[row] = (float)(__float_as_uint(a1) & 1023u);
      float v1 = __uint_as_float(__float_as_uint(a1) & 0xFFFFFC00u);
      float v2 = __uint_as_float(__float_as_uint(a2) & 0xFFFFFC00u);
      if (v1 - v2 < MARGIN_DOT) {
        int pos = atomicAdd(flag_count, 1);
        if (pos < FLAG_CAP) flag_rows[pos] = row;
      }
    }
  }
}

// ---------------- refine: np-f32-pipeline replica (per-code arithmetic identical to R2/R3) ----------------
__global__ __launch_bounds__(64) void vq_refine(const float* __restrict__ z,
                                                const float* __restrict__ emb,
                                                const double* __restrict__ enorm64,
                                                const int* __restrict__ flag_count,
                                                const int* __restrict__ flag_rows,
                                                float* __restrict__ idx_f) {
  __shared__ float zs[64];
  __shared__ float bestv[64];
  __shared__ int bidx[64];
  __shared__ float A32s;
  int cnt = *flag_count;
  if (cnt > FLAG_CAP) cnt = FLAG_CAP;
  int t = threadIdx.x;
  for (int i = blockIdx.x; i < cnt; i += gridDim.x) {
    int row = flag_rows[i];
    zs[t] = z[(size_t)row * 64 + t];
    __syncthreads();
    if (t == 0) {
      double a = 0.0;
      for (int d = 0; d < 64; d++) { double v = (double)zs[d]; a = fma(v, v, a); }
      A32s = (float)a;
    }
    __syncthreads();
    float A32 = A32s;
    float bm = 3.4e38f;
    int bi = 0;
    for (int j = 0; j < 4; j++) {   // 4 codes concurrently: independent f64 chains
      int k0 = t + (j * 4) * 64;
      double dot0 = 0.0, dot1 = 0.0, dot2 = 0.0, dot3 = 0.0;
      for (int d = 0; d < 64; d++) {
        double zv = (double)zs[d];
        dot0 = fma((double)emb[(size_t)(k0      ) * 64 + d], zv, dot0);
        dot1 = fma((double)emb[(size_t)(k0 +  64) * 64 + d], zv, dot1);
        dot2 = fma((double)emb[(size_t)(k0 + 128) * 64 + d], zv, dot2);
        dot3 = fma((double)emb[(size_t)(k0 + 192) * 64 + d], zv, dot3);
      }
      double dots[4] = {dot0, dot1, dot2, dot3};
#pragma unroll
      for (int q = 0; q < 4; q++) {
        int k = k0 + q * 64;
        float C = (float)(2.0 * dots[q]);
        float B = (float)enorm64[k];
        float T = A32 + B;
        float dist = T - C;
        if (dist < bm) { bm = dist; bi = k; }  // ascending k per thread: strict < = lowest
      }
    }
    bestv[t] = bm; bidx[t] = bi;
    __syncthreads();
    if (t == 0) {
      float m = bestv[0]; int ix = bidx[0];
      for (int l = 1; l < 64; l++)
        if (bestv[l] < m || (bestv[l] == m && bidx[l] < ix)) { m = bestv[l]; ix = bidx[l]; }
      idx_f[row] = (float)ix;
    }
    __syncthreads();
  }
}

// ---------------- outputs: quantized_ste + per-block loss partials ----------------
__global__ __launch_bounds__(256) void vq_outputs(
    const float4* __restrict__ z4, const float4* __restrict__ emb4,
    const float* __restrict__ idx_f, float4* __restrict__ out4,
    double* __restrict__ partials) {
  const int tid = threadIdx.x;
  const int g0 = blockIdx.x * 256 + tid;
  double sum = 0.0;
#pragma unroll
  for (int it = 0; it < 4; ++it) {
    int e = g0 + it * (OUT_BLOCKS * 256);
    int row = e >> 4;
    int d4 = e & 15;
    int k = (int)idx_f[row];
    float4 zv = z4[e];
    float4 qv = emb4[k * 16 + d4];
    float dx = qv.x - zv.x, dy = qv.y - zv.y;
    float dz = qv.z - zv.z, dw = qv.w - zv.w;
    float4 o;
    o.x = zv.x + dx; o.y = zv.y + dy; o.z = zv.z + dz; o.w = zv.w + dw;
    out4[e] = o;
    sum += (double)dx * dx + (double)dy * dy + (double)dz * dz + (double)dw * dw;
  }
  for (int off = 32; off > 0; off >>= 1) sum += __shfl_down(sum, off, 64);
  __shared__ double wsum[4];
  if ((tid & 63) == 0) wsum[tid >> 6] = sum;
  __syncthreads();
  if (tid == 0) partials[blockIdx.x] = wsum[0] + wsum[1] + wsum[2] + wsum[3];
}

__global__ __launch_bounds__(256) void vq_final(const double* __restrict__ partials,
                                                float* __restrict__ out_loss) {
  int t = threadIdx.x;
  double s = 0.0;
  for (int i = t; i < OUT_BLOCKS; i += 256) s += partials[i];
  for (int off = 32; off > 0; off >>= 1) s += __shfl_down(s, off, 64);
  __shared__ double wsum[4];
  if ((t & 63) == 0) wsum[t >> 6] = s;
  __syncthreads();
  if (t == 0)
    *out_loss = (float)(1.5 * (wsum[0] + wsum[1] + wsum[2] + wsum[3]) /
                        (double)((size_t)NROWS * DIM));
}

extern "C" void kernel_launch(void* const* d_in, const int* in_sizes, int n_in,
                              void* d_out, int out_size, void* d_ws, size_t ws_size,
                              hipStream_t stream) {
  const float* z = (const float*)d_in[0];
  const float* emb = (const float*)d_in[1];
  float* out = (float*)d_out;
  float* out_q = out;                      // 8388608 floats
  float* out_loss = out + 8388608;         // 1 float
  float* idx_f = out + 8388609;            // 131072 floats

  char* ws = (char*)d_ws;
  double* partials = (double*)ws;                              // [0, 16384)
  double* enorm64 = (double*)(ws + 16384);                     // [16384, 24576)
  int* flag_count = (int*)(ws + 24576);                        // 16 B
  unsigned short* e_hi = (unsigned short*)(ws + 24592);        // 128 KB
  unsigned short* e_lo = (unsigned short*)(ws + 24592 + 131072);  // 128 KB
  int* flag_rows = (int*)(ws + 24592 + 262144);                // 64 KB

  vq_init<<<1, 1, 0, stream>>>(flag_count);
  vq_prep<<<KCODES, 64, 0, stream>>>(emb, enorm64, e_hi, e_lo);
  vq_passB<<<NROWS / 256, 256, 0, stream>>>(z, e_hi, e_lo, idx_f, flag_count, flag_rows);
  vq_refine<<<512, 64, 0, stream>>>(z, emb, enorm64, flag_count, flag_rows, idx_f);
  vq_outputs<<<OUT_BLOCKS, 256, 0, stream>>>((const float4*)z, (const float4*)emb,
                                             idx_f, (float4*)out_q, partials);
  vq_final<<<1, 256, 0, stream>>>(partials, out_loss);
}

// Round 5
// 153.760 us; speedup vs baseline: 5.5141x; 1.7194x over previous
//
#include <hip/hip_runtime.h>

#define NROWS 131072
#define DIM 64
#define KCODES 1024
#define MARGIN_DOT 2.5e-3f
#define WIN_FILTER 5e-4f
#define FLAG_CAP 16384
#define OUT_BLOCKS 2048
#define REFINE_BLOCKS 2048

typedef short bf16x8 __attribute__((ext_vector_type(8)));
typedef float f32x4 __attribute__((ext_vector_type(4)));

__device__ __forceinline__ unsigned short f32_to_bf16_rne(float f) {
  unsigned u = __float_as_uint(f);
  u += 0x7FFFu + ((u >> 16) & 1u);
  return (unsigned short)(u >> 16);
}

// ---------------- init ----------------
__global__ void vq_init(int* flag_count) { *flag_count = 0; }

// ---------------- prep: enorm64 + split-bf16 emb planes ----------------
__global__ __launch_bounds__(64) void vq_prep(const float* __restrict__ emb,
                                              double* __restrict__ enorm64,
                                              unsigned short* __restrict__ e_hi,
                                              unsigned short* __restrict__ e_lo) {
  int k = blockIdx.x;
  int d = threadIdx.x;
  float v = emb[k * 64 + d];
  unsigned short h = f32_to_bf16_rne(v);
  float hf = __uint_as_float((unsigned)h << 16);
  e_hi[k * 64 + d] = h;
  e_lo[k * 64 + d] = f32_to_bf16_rne(v - hf);
  double s = (double)v * (double)v;
  for (int off = 32; off > 0; off >>= 1) s += __shfl_down(s, off, 64);
  if (d == 0) enorm64[k] = s;
}

// ---------------- pass B: split-bf16 MFMA argmax-dot + packed top-2 ----------------
// 512 blocks x 4 waves; wave owns 64 rows x all 1024 codes. No LDS, no barriers.
__global__ __launch_bounds__(256) void vq_passB(
    const float* __restrict__ z, const unsigned short* __restrict__ e_hi,
    const unsigned short* __restrict__ e_lo, float* __restrict__ idx_f,
    int* __restrict__ flag_count, int* __restrict__ flag_rows) {
  const int lane = threadIdx.x & 63;
  const int wv = threadIdx.x >> 6;
  const int rowbase = (blockIdx.x * 4 + wv) * 64;
  const int lo4 = lane & 15;
  const int hi4 = lane >> 4;

  bf16x8 zh[4][2], zl[4][2];
#pragma unroll
  for (int rt = 0; rt < 4; rt++) {
    const float* zr = z + (size_t)(rowbase + rt * 16 + lo4) * 64;
#pragma unroll
    for (int ks = 0; ks < 2; ks++) {
      int d0 = ks * 32 + hi4 * 8;
      float4 f0 = *(const float4*)(zr + d0);
      float4 f1 = *(const float4*)(zr + d0 + 4);
      float fv[8] = {f0.x, f0.y, f0.z, f0.w, f1.x, f1.y, f1.z, f1.w};
      union { bf16x8 v; unsigned short u[8]; } H, L;
#pragma unroll
      for (int i = 0; i < 8; i++) {
        unsigned short h = f32_to_bf16_rne(fv[i]);
        float hf = __uint_as_float((unsigned)h << 16);
        H.u[i] = h;
        L.u[i] = f32_to_bf16_rne(fv[i] - hf);
      }
      zh[rt][ks] = H.v;
      zl[rt][ks] = L.v;
    }
  }

  float m1[4], m2[4];
#pragma unroll
  for (int rt = 0; rt < 4; rt++) { m1[rt] = -3.4e38f; m2[rt] = -3.4e38f; }

  const unsigned short* pH = e_hi + (size_t)lo4 * 64 + hi4 * 8;
  const unsigned short* pL = e_lo + (size_t)lo4 * 64 + hi4 * 8;
  bf16x8 ah0 = *(const bf16x8*)(pH);
  bf16x8 ah1 = *(const bf16x8*)(pH + 32);
  bf16x8 al0 = *(const bf16x8*)(pL);
  bf16x8 al1 = *(const bf16x8*)(pL + 32);

  for (int ct = 0; ct < 64; ct++) {
    int nxt = (ct < 63 ? ct + 1 : 63) * (16 * 64);
    bf16x8 nh0 = *(const bf16x8*)(pH + nxt);
    bf16x8 nh1 = *(const bf16x8*)(pH + nxt + 32);
    bf16x8 nl0 = *(const bf16x8*)(pL + nxt);
    bf16x8 nl1 = *(const bf16x8*)(pL + nxt + 32);
    const int cbase = ct * 16 + hi4 * 4;
#pragma unroll
    for (int rt = 0; rt < 4; rt++) {
      f32x4 acc = {0.f, 0.f, 0.f, 0.f};
      acc = __builtin_amdgcn_mfma_f32_16x16x32_bf16(ah0, zh[rt][0], acc, 0, 0, 0);
      acc = __builtin_amdgcn_mfma_f32_16x16x32_bf16(ah1, zh[rt][1], acc, 0, 0, 0);
      acc = __builtin_amdgcn_mfma_f32_16x16x32_bf16(al0, zh[rt][0], acc, 0, 0, 0);
      acc = __builtin_amdgcn_mfma_f32_16x16x32_bf16(al1, zh[rt][1], acc, 0, 0, 0);
      acc = __builtin_amdgcn_mfma_f32_16x16x32_bf16(ah0, zl[rt][0], acc, 0, 0, 0);
      acc = __builtin_amdgcn_mfma_f32_16x16x32_bf16(ah1, zl[rt][1], acc, 0, 0, 0);
#pragma unroll
      for (int r = 0; r < 4; r++) {
        unsigned cu = (__float_as_uint(acc[r]) & 0xFFFFFC00u) | (unsigned)(cbase + r);
        float p = __uint_as_float(cu);
        float pm = fminf(m1[rt], p);
        m1[rt] = fmaxf(m1[rt], p);
        m2[rt] = fmaxf(m2[rt], pm);
      }
    }
    ah0 = nh0; ah1 = nh1; al0 = nl0; al1 = nl1;
  }

#pragma unroll
  for (int rt = 0; rt < 4; rt++) {
    float a1 = m1[rt], a2 = m2[rt];
#pragma unroll
    for (int off = 16; off <= 32; off <<= 1) {
      float b1 = __shfl_xor(a1, off, 64);
      float b2 = __shfl_xor(a2, off, 64);
      float pm = fminf(a1, b1);
      a1 = fmaxf(a1, b1);
      a2 = fmaxf(fmaxf(a2, b2), pm);
    }
    if (lane < 16) {
      int row = rowbase + rt * 16 + lane;
      idx_f[row] = (float)(__float_as_uint(a1) & 1023u);
      float v1 = __uint_as_float(__float_as_uint(a1) & 0xFFFFFC00u);
      float v2 = __uint_as_float(__float_as_uint(a2) & 0xFFFFFC00u);
      if (v1 - v2 < MARGIN_DOT) {
        int pos = atomicAdd(flag_count, 1);
        if (pos < FLAG_CAP) flag_rows[pos] = row;
      }
    }
  }
}

// ---------------- refine: f32 candidate filter + f64 eval of candidates ----------------
// One block (256 thr) per flagged row. Filter: 4 codes/thread f32 scan -> LDS
// candidate list (codes within WIN_FILTER of best). Eval: coalesced f64 dot per
// candidate (wave-0 tree reduce; f64 order-independent to ~1e-14), then the
// R2-proven np-f32 rounding pipeline with lowest-index tie-break.
__global__ __launch_bounds__(256) void vq_refine(const float* __restrict__ z,
                                                 const float* __restrict__ emb,
                                                 const double* __restrict__ enorm64,
                                                 const int* __restrict__ flag_count,
                                                 const int* __restrict__ flag_rows,
                                                 float* __restrict__ idx_f) {
  __shared__ float zs[64];
  __shared__ float smin[256];
  __shared__ int cand[256];
  __shared__ int ccount;
  __shared__ float A32s;
  int cnt = *flag_count;
  if (cnt > FLAG_CAP) cnt = FLAG_CAP;
  const int t = threadIdx.x;
  for (int i = blockIdx.x; i < cnt; i += gridDim.x) {
    int row = flag_rows[i];
    if (t < 64) zs[t] = z[(size_t)row * 64 + t];
    if (t == 0) ccount = 0;
    __syncthreads();
    if (t == 0) {  // sequential f64 row norm -> f32 (proven path)
      double a = 0.0;
      for (int d = 0; d < 64; d++) { double v = (double)zs[d]; a = fma(v, v, a); }
      A32s = (float)a;
    }
    // f32 filter: thread t scans codes 4t..4t+3, score = -dot
    float s_loc[4];
    float my = 3.4e38f;
#pragma unroll
    for (int q = 0; q < 4; q++) {
      int k = t * 4 + q;
      const float4* er = (const float4*)(emb + (size_t)k * 64);
      float dotf = 0.f;
#pragma unroll
      for (int d4 = 0; d4 < 16; d4++) {
        float4 e4 = er[d4];
        float4 zv = ((const float4*)zs)[d4];
        dotf = fmaf(e4.x, zv.x, dotf);
        dotf = fmaf(e4.y, zv.y, dotf);
        dotf = fmaf(e4.z, zv.z, dotf);
        dotf = fmaf(e4.w, zv.w, dotf);
      }
      s_loc[q] = -dotf;
      my = fminf(my, -dotf);
    }
    smin[t] = my;
    __syncthreads();
    for (int s = 128; s > 0; s >>= 1) {
      if (t < s) smin[t] = fminf(smin[t], smin[t + s]);
      __syncthreads();
    }
    float m1 = smin[0];
#pragma unroll
    for (int q = 0; q < 4; q++) {
      if (s_loc[q] - m1 < WIN_FILTER) {
        int p = atomicAdd(&ccount, 1);
        if (p < 256) cand[p] = t * 4 + q;
      }
    }
    __syncthreads();
    int cc = ccount;
    if (cc > 256) cc = 256;
    if (t < 64) {
      float bm = 3.4e38f;
      int bi = 0x7FFFFFFF;
      for (int c = 0; c < cc; c++) {
        int k = cand[c];
        double p = (double)emb[(size_t)k * 64 + t] * (double)zs[t];
        for (int off = 32; off > 0; off >>= 1) p += __shfl_down(p, off, 64);
        if (t == 0) {
          float C = (float)(2.0 * p);
          float B = (float)enorm64[k];
          float T = A32s + B;
          float dist = T - C;
          if (dist < bm || (dist == bm && k < bi)) { bm = dist; bi = k; }
        }
      }
      if (t == 0) idx_f[row] = (float)bi;
    }
    __syncthreads();
  }
}

// ---------------- outputs: quantized_ste + per-block loss partials ----------------
__global__ __launch_bounds__(256) void vq_outputs(
    const float4* __restrict__ z4, const float4* __restrict__ emb4,
    const float* __restrict__ idx_f, float4* __restrict__ out4,
    double* __restrict__ partials) {
  const int tid = threadIdx.x;
  const int g0 = blockIdx.x * 256 + tid;
  double sum = 0.0;
#pragma unroll
  for (int it = 0; it < 4; ++it) {
    int e = g0 + it * (OUT_BLOCKS * 256);
    int row = e >> 4;
    int d4 = e & 15;
    int k = (int)idx_f[row];
    float4 zv = z4[e];
    float4 qv = emb4[k * 16 + d4];
    float dx = qv.x - zv.x, dy = qv.y - zv.y;
    float dz = qv.z - zv.z, dw = qv.w - zv.w;
    float4 o;
    o.x = zv.x + dx; o.y = zv.y + dy; o.z = zv.z + dz; o.w = zv.w + dw;
    out4[e] = o;
    sum += (double)dx * dx + (double)dy * dy + (double)dz * dz + (double)dw * dw;
  }
  for (int off = 32; off > 0; off >>= 1) sum += __shfl_down(sum, off, 64);
  __shared__ double wsum[4];
  if ((tid & 63) == 0) wsum[tid >> 6] = sum;
  __syncthreads();
  if (tid == 0) partials[blockIdx.x] = wsum[0] + wsum[1] + wsum[2] + wsum[3];
}

__global__ __launch_bounds__(256) void vq_final(const double* __restrict__ partials,
                                                float* __restrict__ out_loss) {
  int t = threadIdx.x;
  double s = 0.0;
  for (int i = t; i < OUT_BLOCKS; i += 256) s += partials[i];
  for (int off = 32; off > 0; off >>= 1) s += __shfl_down(s, off, 64);
  __shared__ double wsum[4];
  if ((t & 63) == 0) wsum[t >> 6] = s;
  __syncthreads();
  if (t == 0)
    *out_loss = (float)(1.5 * (wsum[0] + wsum[1] + wsum[2] + wsum[3]) /
                        (double)((size_t)NROWS * DIM));
}

extern "C" void kernel_launch(void* const* d_in, const int* in_sizes, int n_in,
                              void* d_out, int out_size, void* d_ws, size_t ws_size,
                              hipStream_t stream) {
  const float* z = (const float*)d_in[0];
  const float* emb = (const float*)d_in[1];
  float* out = (float*)d_out;
  float* out_q = out;                      // 8388608 floats
  float* out_loss = out + 8388608;         // 1 float
  float* idx_f = out + 8388609;            // 131072 floats

  char* ws = (char*)d_ws;
  double* partials = (double*)ws;                              // [0, 16384)
  double* enorm64 = (double*)(ws + 16384);                     // [16384, 24576)
  int* flag_count = (int*)(ws + 24576);                        // 16 B
  unsigned short* e_hi = (unsigned short*)(ws + 24592);        // 128 KB
  unsigned short* e_lo = (unsigned short*)(ws + 24592 + 131072);  // 128 KB
  int* flag_rows = (int*)(ws + 24592 + 262144);                // 64 KB

  vq_init<<<1, 1, 0, stream>>>(flag_count);
  vq_prep<<<KCODES, 64, 0, stream>>>(emb, enorm64, e_hi, e_lo);
  vq_passB<<<NROWS / 256, 256, 0, stream>>>(z, e_hi, e_lo, idx_f, flag_count, flag_rows);
  vq_refine<<<REFINE_BLOCKS, 256, 0, stream>>>(z, emb, enorm64, flag_count, flag_rows, idx_f);
  vq_outputs<<<OUT_BLOCKS, 256, 0, stream>>>((const float4*)z, (const float4*)emb,
                                             idx_f, (float4*)out_q, partials);
  vq_final<<<1, 256, 0, stream>>>(partials, out_loss);
}